// Round 1
// 726.635 us; speedup vs baseline: 1.1119x; 1.1119x over previous
//
#include <hip/hip_runtime.h>
#include <math.h>

#define N_ROWS 50000
#define DIM 512

#define BM 128
#define BN 64
#define BK 32
#define KSTEPS (DIM / BK)     // 16
#define N_STRIPS 391          // ceil(50000/128)
#define STRIPS_PER_XCD 49     // ceil(391/8)
#define LDA 40                // padded LDS row stride (elems). 80 B = 5 granules of 16 B,
                              // 5 coprime with 8 -> conflict-free b128 reads AND writes.

typedef __attribute__((ext_vector_type(8))) short short8;
typedef __attribute__((ext_vector_type(4))) float float4v;

__device__ inline unsigned short f2bf(float x) {
    union { float f; unsigned u; } v; v.f = x;
    unsigned r = v.u + 0x7fffu + ((v.u >> 16) & 1u);  // RNE
    return (unsigned short)(r >> 16);
}

__device__ inline short8 packv(float4v x, float4v y) {
    short8 r;
    r[0] = (short)f2bf(x[0]); r[1] = (short)f2bf(x[1]);
    r[2] = (short)f2bf(x[2]); r[3] = (short)f2bf(x[3]);
    r[4] = (short)f2bf(y[0]); r[5] = (short)f2bf(y[1]);
    r[6] = (short)f2bf(y[2]); r[7] = (short)f2bf(y[3]);
    return r;
}

// tanh via hw exp + rcp: ~7 VALU ops vs ~20+ for ocml tanhf.
__device__ inline float fast_tanh(float x) {
    float xc = fminf(fmaxf(x, -15.f), 15.f);
    float e = __expf(2.0f * xc);
    return 1.0f - 2.0f * __builtin_amdgcn_rcpf(e + 1.0f);
}

// ---- K1-lite: only W fp32->bf16 (3 MB read / 1.5 MB write, ~5 us) + zero sums.
// The 360 MB embed-conversion pass is gone: the GEMM kernel converts in-register.
__global__ __launch_bounds__(256) void convert_w(
    const float* __restrict__ Wi, const float* __restrict__ Wp, const float* __restrict__ Ws,
    unsigned short* __restrict__ Wi_bf, unsigned short* __restrict__ Wp_bf,
    unsigned short* __restrict__ Ws_bf, float* __restrict__ sums)
{
    const int t = blockIdx.x * 256 + threadIdx.x;   // 0..98303 (3*512*512/8)
    if (t < 3) sums[t] = 0.0f;
    const int mat = t >> 15;
    const size_t idx = (size_t)(t & 32767) * 8;
    const float* src = (mat == 0) ? Wi : ((mat == 1) ? Wp : Ws);
    unsigned short* dst = (mat == 0) ? Wi_bf : ((mat == 1) ? Wp_bf : Ws_bf);
    float4v a = *(const float4v*)(src + idx);
    float4v b = *(const float4v*)(src + idx + 4);
    *(short8*)(dst + idx) = packv(a, b);
}

// ---- K2: fully fused. fp32 A staged to regs -> bf16 -> padded LDS; software-
// pipelined with raw s_barrier + lgkmcnt-only wait so the next tile's global
// loads stay in flight across the MFMA phase (vmcnt never drained in the loop).
__global__ __launch_bounds__(256, 2) void fused_all(
    const float* __restrict__ img, const float* __restrict__ ph,
    const unsigned short* __restrict__ Wi_bf, const unsigned short* __restrict__ Wp_bf,
    const unsigned short* __restrict__ Ws_bf,
    const float* __restrict__ bs, const float* __restrict__ bi, const float* __restrict__ bp,
    float* __restrict__ out, float* __restrict__ sums)
{
    const int bid = blockIdx.x;
    const int xcd = bid & 7;
    const int u   = bid >> 3;
    const int col = u & 7;              // col-tile fastest within an XCD slab
    const int s   = u >> 3;
    const int strip = xcd * STRIPS_PER_XCD + s;
    if (strip >= N_STRIPS) return;
    const int e0 = col * BN;
    const int n0 = strip * BM;

    __shared__ __align__(16) unsigned short sA[3][BM][LDA];  // 30 KB
    __shared__ __align__(16) unsigned short sB[3][BN][LDA];  // 15 KB

    const int tid  = threadIdx.x;
    const int lane = tid & 63;
    const int wid  = tid >> 6;
    const int wm   = wid & 1;           // 64-row half
    const int wn   = wid >> 1;          // 32-col half
    const int l15  = lane & 15;
    const int quad = lane >> 4;

    // staging ownership: thread owns half a row of the 128x32 A tile (16 floats),
    // and one 16 B chunk of each 64x32 B tile.
    const int ar = tid >> 1;                         // 0..127
    const int ah = tid & 1;                          // 16-float half
    const int arow = n0 + ar;
    const bool avalid = arow < N_ROWS;               // last strip covers rows >= 50000
    const size_t abase = (size_t)arow * DIM + ah * 16;
    const int br = tid >> 2;                         // 0..63
    const int bc = (tid & 3) * 8;
    const size_t bbase = (size_t)(e0 + br) * DIM + bc;

    const unsigned short* Bmat[3] = { Wi_bf, Wp_bf, Ws_bf };

    float4v aI[4], aP[4];
    short8 bW[3];
#pragma unroll
    for (int q = 0; q < 4; ++q) { aI[q] = (float4v){0,0,0,0}; aP[q] = (float4v){0,0,0,0}; }

#define LOADK(k0_) do {                                                     \
        const int k0v = (k0_);                                              \
        if (avalid) {                                                       \
            const float* gi = img + abase + k0v;                            \
            const float* gp = ph  + abase + k0v;                            \
            aI[0] = *(const float4v*)(gi);      aI[1] = *(const float4v*)(gi + 4);  \
            aI[2] = *(const float4v*)(gi + 8);  aI[3] = *(const float4v*)(gi + 12); \
            aP[0] = *(const float4v*)(gp);      aP[1] = *(const float4v*)(gp + 4);  \
            aP[2] = *(const float4v*)(gp + 8);  aP[3] = *(const float4v*)(gp + 12); \
        }                                                                   \
        bW[0] = *(const short8*)(Bmat[0] + bbase + k0v);                    \
        bW[1] = *(const short8*)(Bmat[1] + bbase + k0v);                    \
        bW[2] = *(const short8*)(Bmat[2] + bbase + k0v);                    \
    } while (0)

    float4v acc[3][4][2];
#pragma unroll
    for (int m = 0; m < 3; ++m)
#pragma unroll
        for (int i = 0; i < 4; ++i)
#pragma unroll
            for (int j = 0; j < 2; ++j)
                acc[m][i][j] = (float4v){0.f, 0.f, 0.f, 0.f};

    LOADK(0);

#pragma unroll 1
    for (int kb = 0; kb < KSTEPS; ++kb) {
        // barrier A: all waves finished ds_reading the previous tile (their frag
        // reads completed before their MFMAs issued). Raw barrier: the in-flight
        // global loads are NOT drained here.
        asm volatile("" ::: "memory");
        __builtin_amdgcn_s_barrier();
        asm volatile("" ::: "memory");

        // stage: fp32->bf16 convert + padded ds_write. Compiler inserts the
        // vmcnt waits for aI/aP/bW here (issued one iteration ago, hidden
        // under the previous tile's MFMA phase).
        {
            float4v s0 = 0.5f * (aI[0] + aP[0]);
            float4v s1 = 0.5f * (aI[1] + aP[1]);
            float4v s2 = 0.5f * (aI[2] + aP[2]);
            float4v s3 = 0.5f * (aI[3] + aP[3]);
            *(short8*)&sA[0][ar][ah * 16]     = packv(aI[0], aI[1]);
            *(short8*)&sA[0][ar][ah * 16 + 8] = packv(aI[2], aI[3]);
            *(short8*)&sA[1][ar][ah * 16]     = packv(aP[0], aP[1]);
            *(short8*)&sA[1][ar][ah * 16 + 8] = packv(aP[2], aP[3]);
            *(short8*)&sA[2][ar][ah * 16]     = packv(s0, s1);
            *(short8*)&sA[2][ar][ah * 16 + 8] = packv(s2, s3);
            *(short8*)&sB[0][br][bc] = bW[0];
            *(short8*)&sB[1][br][bc] = bW[1];
            *(short8*)&sB[2][br][bc] = bW[2];
        }

        // issue next tile's global loads NOW; they remain in flight across
        // barrier B and the whole MFMA phase.
        if (kb + 1 < KSTEPS) LOADK((kb + 1) * BK);

        // barrier B: ds_writes visible. Wait LDS counter only — vmcnt untouched.
        asm volatile("s_waitcnt lgkmcnt(0)" ::: "memory");
        __builtin_amdgcn_s_barrier();
        asm volatile("" ::: "memory");

#pragma unroll
        for (int mat = 0; mat < 3; ++mat) {
            short8 a[4], b[2];
#pragma unroll
            for (int i = 0; i < 4; ++i)
                a[i] = *(const short8*)&sA[mat][wm * 64 + i * 16 + l15][quad * 8];
#pragma unroll
            for (int j = 0; j < 2; ++j)
                b[j] = *(const short8*)&sB[mat][wn * 32 + j * 16 + l15][quad * 8];
#pragma unroll
            for (int i = 0; i < 4; ++i)
#pragma unroll
                for (int j = 0; j < 2; ++j)
                    acc[mat][i][j] = __builtin_amdgcn_mfma_f32_16x16x32_bf16(
                        a[i], b[j], acc[mat][i][j], 0, 0, 0);
        }
    }
#undef LOADK

    // ---- epilogue: tanh + joint combine + Frobenius partial sums.
    // Reads fp32 embeds directly (rows are L2-hot from the k-loop).
    float s_i = 0.f, s_p = 0.f, s_s = 0.f;
#pragma unroll
    for (int i = 0; i < 4; ++i) {
#pragma unroll
        for (int j = 0; j < 2; ++j) {
            const int c = e0 + wn * 32 + j * 16 + l15;
            const float bii = bi[c], bpp = bp[c], bss = bs[c];
            const int rbase = n0 + wm * 64 + i * 16 + quad * 4;
#pragma unroll
            for (int r = 0; r < 4; ++r) {
                const int nrow = rbase + r;
                const float ia = fast_tanh(acc[0][i][j][r] + bii);
                const float pa = fast_tanh(acc[1][i][j][r] + bpp);
                const float sa = fast_tanh(acc[2][i][j][r] + bss);
                if (nrow < N_ROWS) {
                    const size_t off = (size_t)nrow * DIM + c;
                    const float ie = img[off];
                    const float pe = ph[off];
                    const float se = 0.5f * (ie + pe);
                    out[off] = sa * se + ia * ie + pa * pe;
                    s_i += ia * ia; s_p += pa * pa; s_s += sa * sa;
                }
            }
        }
    }

#pragma unroll
    for (int off = 32; off > 0; off >>= 1) {
        s_i += __shfl_down(s_i, off);
        s_p += __shfl_down(s_p, off);
        s_s += __shfl_down(s_s, off);
    }
    if (lane == 0) {
        atomicAdd(&sums[0], s_i);
        atomicAdd(&sums[1], s_p);
        atomicAdd(&sums[2], s_s);
    }
}

__global__ void finalize(const float* __restrict__ sums, float* __restrict__ wout) {
    if (threadIdx.x == 0) {
        const float inv_sh = 1.0f / sums[2];
        const float is = sums[0] * inv_sh;
        const float ps = sums[1] * inv_sh;
        const float m  = fmaxf(is, ps);
        const float ei = expf(is - m), ep = expf(ps - m);
        const float inv = 1.0f / (ei + ep);
        wout[0] = ei * inv;
        wout[1] = ep * inv;
    }
}

extern "C" void kernel_launch(void* const* d_in, const int* in_sizes, int n_in,
                              void* d_out, int out_size, void* d_ws, size_t ws_size,
                              hipStream_t stream) {
    const float* img = (const float*)d_in[0];
    const float* ph  = (const float*)d_in[1];
    const float* Ws  = (const float*)d_in[2];
    const float* bs  = (const float*)d_in[3];
    const float* Wi  = (const float*)d_in[4];
    const float* bi  = (const float*)d_in[5];
    const float* Wp  = (const float*)d_in[6];
    const float* bp  = (const float*)d_in[7];
    float* out  = (float*)d_out;
    float* sums = (float*)d_ws;

    const size_t w_elems = (size_t)DIM * DIM;
    unsigned short* Wi_bf = (unsigned short*)((char*)d_ws + 256);
    unsigned short* Wp_bf = Wi_bf + w_elems;
    unsigned short* Ws_bf = Wp_bf + w_elems;

    convert_w<<<384, 256, 0, stream>>>(Wi, Wp, Ws, Wi_bf, Wp_bf, Ws_bf, sums);

    // 8 xcds x 49 strips x 8 cols = 3136 blocks (8 no-ops where strip >= 391)
    fused_all<<<8 * STRIPS_PER_XCD * 8, 256, 0, stream>>>(
        img, ph, Wi_bf, Wp_bf, Ws_bf, bs, bi, bp, out, sums);

    finalize<<<1, 64, 0, stream>>>(sums, out + (size_t)N_ROWS * DIM);
}

// Round 2
// 500.709 us; speedup vs baseline: 1.6136x; 1.4512x over previous
//
#include <hip/hip_runtime.h>
#include <math.h>

#define N_ROWS 50000
#define DIM 512

#define BM 128
#define BN 64
#define BK 32
#define KSTEPS (DIM / BK)     // 16
#define N_STRIPS 391          // ceil(50000/128)
#define STRIPS_PER_XCD 49     // ceil(391/8)
#define LDA 40                // padded LDS row stride (elems). 80 B = 5 granules of 16 B,
                              // 5 coprime with 8 -> no power-of-2 bank aliasing on b128.
#define GRID_K2 (8 * STRIPS_PER_XCD * 8)   // 3136 blocks
#define NSLOTS (GRID_K2 * 4)               // per-WAVE partial-sum slots (float4 each)

typedef __attribute__((ext_vector_type(8))) short short8;
typedef __attribute__((ext_vector_type(4))) float float4v;

__device__ inline unsigned short f2bf(float x) {
    union { float f; unsigned u; } v; v.f = x;
    unsigned r = v.u + 0x7fffu + ((v.u >> 16) & 1u);  // RNE
    return (unsigned short)(r >> 16);
}

__device__ inline short8 packv(float4v x, float4v y) {
    short8 r;
    r[0] = (short)f2bf(x[0]); r[1] = (short)f2bf(x[1]);
    r[2] = (short)f2bf(x[2]); r[3] = (short)f2bf(x[3]);
    r[4] = (short)f2bf(y[0]); r[5] = (short)f2bf(y[1]);
    r[6] = (short)f2bf(y[2]); r[7] = (short)f2bf(y[3]);
    return r;
}

// tanh via hw exp + rcp: ~7 VALU ops vs ~20+ for ocml tanhf.
__device__ inline float fast_tanh(float x) {
    float xc = fminf(fmaxf(x, -15.f), 15.f);
    float e = __expf(2.0f * xc);
    return 1.0f - 2.0f * __builtin_amdgcn_rcpf(e + 1.0f);
}

// ---- K1-lite: only W fp32->bf16 (3 MB read / 1.5 MB write, ~5 us).
__global__ __launch_bounds__(256) void convert_w(
    const float* __restrict__ Wi, const float* __restrict__ Wp, const float* __restrict__ Ws,
    unsigned short* __restrict__ Wi_bf, unsigned short* __restrict__ Wp_bf,
    unsigned short* __restrict__ Ws_bf)
{
    const int t = blockIdx.x * 256 + threadIdx.x;   // 0..98303 (3*512*512/8)
    const int mat = t >> 15;
    const size_t idx = (size_t)(t & 32767) * 8;
    const float* src = (mat == 0) ? Wi : ((mat == 1) ? Wp : Ws);
    unsigned short* dst = (mat == 0) ? Wi_bf : ((mat == 1) ? Wp_bf : Ws_bf);
    float4v a = *(const float4v*)(src + idx);
    float4v b = *(const float4v*)(src + idx + 4);
    *(short8*)(dst + idx) = packv(a, b);
}

// ---- K2: fused triple GEMM + tanh + combine. Partial sums now go to PRIVATE
// per-wave slots via plain float4 stores — the 37632 same-line device atomics
// (the suspected ~565 us serializer) are gone.
__global__ __launch_bounds__(256, 2) void fused_all(
    const float* __restrict__ img, const float* __restrict__ ph,
    const unsigned short* __restrict__ Wi_bf, const unsigned short* __restrict__ Wp_bf,
    const unsigned short* __restrict__ Ws_bf,
    const float* __restrict__ bs, const float* __restrict__ bi, const float* __restrict__ bp,
    float* __restrict__ out, float* __restrict__ part)
{
    const int bid = blockIdx.x;
    const int tid = threadIdx.x;
    const int xcd = bid & 7;
    const int u   = bid >> 3;
    const int col = u & 7;              // col-tile fastest within an XCD slab
    const int s   = u >> 3;
    const int strip = xcd * STRIPS_PER_XCD + s;
    if (strip >= N_STRIPS) {            // 8 no-op blocks: zero their slots
        if (tid < 4) {
            float4v z = {0.f, 0.f, 0.f, 0.f};
            *(float4v*)(part + ((size_t)bid * 4 + tid) * 4) = z;
        }
        return;
    }
    const int e0 = col * BN;
    const int n0 = strip * BM;

    __shared__ __align__(16) unsigned short sA[3][BM][LDA];  // 30 KB
    __shared__ __align__(16) unsigned short sB[3][BN][LDA];  // 15 KB

    const int lane = tid & 63;
    const int wid  = tid >> 6;
    const int wm   = wid & 1;           // 64-row half
    const int wn   = wid >> 1;          // 32-col half
    const int l15  = lane & 15;
    const int quad = lane >> 4;

    // staging ownership: thread owns half a row of the 128x32 A tile (16 floats),
    // and one 16 B chunk of each 64x32 B tile.
    const int ar = tid >> 1;                         // 0..127
    const int ah = tid & 1;                          // 16-float half
    const int arow = n0 + ar;
    const bool avalid = arow < N_ROWS;               // last strip covers rows >= 50000
    const size_t abase = (size_t)arow * DIM + ah * 16;
    const int br = tid >> 2;                         // 0..63
    const int bc = (tid & 3) * 8;
    const size_t bbase = (size_t)(e0 + br) * DIM + bc;

    const unsigned short* Bmat[3] = { Wi_bf, Wp_bf, Ws_bf };

    float4v aI[4], aP[4];
    short8 bW[3];
#pragma unroll
    for (int q = 0; q < 4; ++q) { aI[q] = (float4v){0,0,0,0}; aP[q] = (float4v){0,0,0,0}; }

#define LOADK(k0_) do {                                                     \
        const int k0v = (k0_);                                              \
        if (avalid) {                                                       \
            const float* gi = img + abase + k0v;                            \
            const float* gp = ph  + abase + k0v;                            \
            aI[0] = *(const float4v*)(gi);      aI[1] = *(const float4v*)(gi + 4);  \
            aI[2] = *(const float4v*)(gi + 8);  aI[3] = *(const float4v*)(gi + 12); \
            aP[0] = *(const float4v*)(gp);      aP[1] = *(const float4v*)(gp + 4);  \
            aP[2] = *(const float4v*)(gp + 8);  aP[3] = *(const float4v*)(gp + 12); \
        }                                                                   \
        bW[0] = *(const short8*)(Bmat[0] + bbase + k0v);                    \
        bW[1] = *(const short8*)(Bmat[1] + bbase + k0v);                    \
        bW[2] = *(const short8*)(Bmat[2] + bbase + k0v);                    \
    } while (0)

    float4v acc[3][4][2];
#pragma unroll
    for (int m = 0; m < 3; ++m)
#pragma unroll
        for (int i = 0; i < 4; ++i)
#pragma unroll
            for (int j = 0; j < 2; ++j)
                acc[m][i][j] = (float4v){0.f, 0.f, 0.f, 0.f};

    LOADK(0);

#pragma unroll 1
    for (int kb = 0; kb < KSTEPS; ++kb) {
        // barrier A: all waves finished ds_reading the previous tile. Raw
        // barrier: in-flight global loads are NOT drained here.
        asm volatile("" ::: "memory");
        __builtin_amdgcn_s_barrier();
        asm volatile("" ::: "memory");

        // stage: fp32->bf16 convert + padded ds_write (vmcnt waits for aI/aP/bW
        // land here, hidden under the previous tile's MFMA phase).
        {
            float4v s0 = 0.5f * (aI[0] + aP[0]);
            float4v s1 = 0.5f * (aI[1] + aP[1]);
            float4v s2 = 0.5f * (aI[2] + aP[2]);
            float4v s3 = 0.5f * (aI[3] + aP[3]);
            *(short8*)&sA[0][ar][ah * 16]     = packv(aI[0], aI[1]);
            *(short8*)&sA[0][ar][ah * 16 + 8] = packv(aI[2], aI[3]);
            *(short8*)&sA[1][ar][ah * 16]     = packv(aP[0], aP[1]);
            *(short8*)&sA[1][ar][ah * 16 + 8] = packv(aP[2], aP[3]);
            *(short8*)&sA[2][ar][ah * 16]     = packv(s0, s1);
            *(short8*)&sA[2][ar][ah * 16 + 8] = packv(s2, s3);
            *(short8*)&sB[0][br][bc] = bW[0];
            *(short8*)&sB[1][br][bc] = bW[1];
            *(short8*)&sB[2][br][bc] = bW[2];
        }

        // issue next tile's global loads NOW; in flight across barrier B + MFMAs.
        if (kb + 1 < KSTEPS) LOADK((kb + 1) * BK);

        // barrier B: ds_writes visible. LDS counter only — vmcnt untouched.
        asm volatile("s_waitcnt lgkmcnt(0)" ::: "memory");
        __builtin_amdgcn_s_barrier();
        asm volatile("" ::: "memory");

#pragma unroll
        for (int mat = 0; mat < 3; ++mat) {
            short8 a[4], b[2];
#pragma unroll
            for (int i = 0; i < 4; ++i)
                a[i] = *(const short8*)&sA[mat][wm * 64 + i * 16 + l15][quad * 8];
#pragma unroll
            for (int j = 0; j < 2; ++j)
                b[j] = *(const short8*)&sB[mat][wn * 32 + j * 16 + l15][quad * 8];
#pragma unroll
            for (int i = 0; i < 4; ++i)
#pragma unroll
                for (int j = 0; j < 2; ++j)
                    acc[mat][i][j] = __builtin_amdgcn_mfma_f32_16x16x32_bf16(
                        a[i], b[j], acc[mat][i][j], 0, 0, 0);
        }
    }
#undef LOADK

    // ---- epilogue: tanh + joint combine + Frobenius partial sums.
    float s_i = 0.f, s_p = 0.f, s_s = 0.f;
#pragma unroll
    for (int i = 0; i < 4; ++i) {
#pragma unroll
        for (int j = 0; j < 2; ++j) {
            const int c = e0 + wn * 32 + j * 16 + l15;
            const float bii = bi[c], bpp = bp[c], bss = bs[c];
            const int rbase = n0 + wm * 64 + i * 16 + quad * 4;
#pragma unroll
            for (int r = 0; r < 4; ++r) {
                const int nrow = rbase + r;
                const float ia = fast_tanh(acc[0][i][j][r] + bii);
                const float pa = fast_tanh(acc[1][i][j][r] + bpp);
                const float sa = fast_tanh(acc[2][i][j][r] + bss);
                if (nrow < N_ROWS) {
                    const size_t off = (size_t)nrow * DIM + c;
                    const float ie = img[off];
                    const float pe = ph[off];
                    const float se = 0.5f * (ie + pe);
                    out[off] = sa * se + ia * ie + pa * pe;
                    s_i += ia * ia; s_p += pa * pa; s_s += sa * sa;
                }
            }
        }
    }

#pragma unroll
    for (int off = 32; off > 0; off >>= 1) {
        s_i += __shfl_down(s_i, off);
        s_p += __shfl_down(s_p, off);
        s_s += __shfl_down(s_s, off);
    }
    // plain per-wave store — no contended atomics anywhere.
    if (lane == 0) {
        float4v v = {s_i, s_p, s_s, 0.f};
        *(float4v*)(part + ((size_t)bid * 4 + wid) * 4) = v;
    }
}

__global__ __launch_bounds__(256) void finalize(
    const float* __restrict__ part, float* __restrict__ wout)
{
    __shared__ float4v red[256];
    float4v acc = {0.f, 0.f, 0.f, 0.f};
    for (int i = threadIdx.x; i < NSLOTS; i += 256)
        acc += *(const float4v*)(part + (size_t)i * 4);
    red[threadIdx.x] = acc;
    __syncthreads();
    for (int s = 128; s > 0; s >>= 1) {
        if (threadIdx.x < s) red[threadIdx.x] += red[threadIdx.x + s];
        __syncthreads();
    }
    if (threadIdx.x == 0) {
        float4v t = red[0];
        const float inv_sh = 1.0f / t[2];
        const float is = t[0] * inv_sh;
        const float ps = t[1] * inv_sh;
        const float m  = fmaxf(is, ps);
        const float ei = expf(is - m), ep = expf(ps - m);
        const float inv = 1.0f / (ei + ep);
        wout[0] = ei * inv;
        wout[1] = ep * inv;
    }
}

extern "C" void kernel_launch(void* const* d_in, const int* in_sizes, int n_in,
                              void* d_out, int out_size, void* d_ws, size_t ws_size,
                              hipStream_t stream) {
    const float* img = (const float*)d_in[0];
    const float* ph  = (const float*)d_in[1];
    const float* Ws  = (const float*)d_in[2];
    const float* bs  = (const float*)d_in[3];
    const float* Wi  = (const float*)d_in[4];
    const float* bi  = (const float*)d_in[5];
    const float* Wp  = (const float*)d_in[6];
    const float* bp  = (const float*)d_in[7];
    float* out  = (float*)d_out;

    const size_t w_elems = (size_t)DIM * DIM;
    unsigned short* Wi_bf = (unsigned short*)((char*)d_ws + 256);
    unsigned short* Wp_bf = Wi_bf + w_elems;
    unsigned short* Ws_bf = Wp_bf + w_elems;
    float* part = (float*)((char*)d_ws + 256 + 3 * w_elems * sizeof(unsigned short));

    convert_w<<<384, 256, 0, stream>>>(Wi, Wp, Ws, Wi_bf, Wp_bf, Ws_bf);

    // 8 xcds x 49 strips x 8 cols = 3136 blocks (8 no-ops where strip >= 391)
    fused_all<<<GRID_K2, 256, 0, stream>>>(
        img, ph, Wi_bf, Wp_bf, Ws_bf, bs, bi, bp, out, part);

    finalize<<<1, 256, 0, stream>>>(part, out + (size_t)N_ROWS * DIM);
}